// Round 1
// baseline (47334.720 us; speedup 1.0000x reference)
//
#include <hip/hip_runtime.h>
#include <hip/hip_bf16.h>

// ---------------------------------------------------------------------------
// MIL_8615704395807: 3-partition R-GCN + attention pooling, full fp32 baseline.
// Sizes: N=112000 nodes, IN=1024, H=512, L=2, NS=3, CAT=1536, D_LAST=4608.
// ---------------------------------------------------------------------------

#define LEAKY(v) ((v) >= 0.f ? (v) : 0.01f * (v))

// ---------------------------------------------------------------------------
// Generic fp32 GEMM: C = epilogue(A @ W + bias), A (M,K) row-major lda=K,
// W (K,N) row-major, C row-major with ldc. Tile 128x128x16, 8x8 per thread.
// Requires M%128==0, N%128==0, K%16==0 (true for every call here).
// EPI: 0=bias, 1=bias+leaky, 2=C+=acc (no bias), 3=bias+tanh,
//      4=C = sigmoid(acc+bias) * C_old
// ---------------------------------------------------------------------------
template <int EPI>
__global__ void __launch_bounds__(256)
gemm_f32(const float* __restrict__ A, const float* __restrict__ W,
         const float* __restrict__ bias, float* __restrict__ C,
         int N, int K, int ldc)
{
    __shared__ float As[16][132];
    __shared__ float Bs[16][132];

    const int tid  = threadIdx.x;
    const int tx   = tid & 15;   // col dir
    const int ty   = tid >> 4;   // row dir
    const int row0 = blockIdx.x * 128;
    const int col0 = blockIdx.y * 128;

    // global-load assignments
    const int am = tid >> 1;            // A tile row 0..127
    const int ak = (tid & 1) * 8;       // A tile k  0 or 8
    const int bk = tid >> 4;            // B tile k 0..15
    const int bn = (tid & 15) * 8;      // B tile col 0..120

    float acc[8][8];
#pragma unroll
    for (int i = 0; i < 8; ++i)
#pragma unroll
        for (int j = 0; j < 8; ++j) acc[i][j] = 0.f;

    const float* Aptr = A + (size_t)(row0 + am) * K + ak;
    const float* Wptr = W + (size_t)bk * N + col0 + bn;

    for (int k0 = 0; k0 < K; k0 += 16) {
        float4 a0 = *(const float4*)(Aptr + k0);
        float4 a1 = *(const float4*)(Aptr + k0 + 4);
        float4 b0 = *(const float4*)(Wptr + (size_t)k0 * N);
        float4 b1 = *(const float4*)(Wptr + (size_t)k0 * N + 4);
        __syncthreads();   // previous iteration's LDS reads must be done
        As[ak + 0][am] = a0.x; As[ak + 1][am] = a0.y;
        As[ak + 2][am] = a0.z; As[ak + 3][am] = a0.w;
        As[ak + 4][am] = a1.x; As[ak + 5][am] = a1.y;
        As[ak + 6][am] = a1.z; As[ak + 7][am] = a1.w;
        *(float4*)&Bs[bk][bn]     = b0;
        *(float4*)&Bs[bk][bn + 4] = b1;
        __syncthreads();
#pragma unroll
        for (int k = 0; k < 16; ++k) {
            float av[8], bv[8];
            *(float4*)&av[0] = *(const float4*)&As[k][ty * 8];
            *(float4*)&av[4] = *(const float4*)&As[k][ty * 8 + 4];
            *(float4*)&bv[0] = *(const float4*)&Bs[k][tx * 4];
            *(float4*)&bv[4] = *(const float4*)&Bs[k][tx * 4 + 64];
#pragma unroll
            for (int i = 0; i < 8; ++i)
#pragma unroll
                for (int j = 0; j < 8; ++j) acc[i][j] += av[i] * bv[j];
        }
    }

#pragma unroll
    for (int i = 0; i < 8; ++i) {
        const int r = row0 + ty * 8 + i;
        float* crow = C + (size_t)r * ldc;
#pragma unroll
        for (int half = 0; half < 2; ++half) {
            const int c = col0 + half * 64 + tx * 4;
            float* ap = &acc[i][half * 4];
            float4 o;
            if (EPI == 2) {
                float4 old = *(float4*)(crow + c);
                o.x = old.x + ap[0]; o.y = old.y + ap[1];
                o.z = old.z + ap[2]; o.w = old.w + ap[3];
            } else if (EPI == 0) {
                o.x = ap[0] + bias[c];     o.y = ap[1] + bias[c + 1];
                o.z = ap[2] + bias[c + 2]; o.w = ap[3] + bias[c + 3];
            } else if (EPI == 1) {
                float v0 = ap[0] + bias[c], v1 = ap[1] + bias[c + 1];
                float v2 = ap[2] + bias[c + 2], v3 = ap[3] + bias[c + 3];
                o.x = LEAKY(v0); o.y = LEAKY(v1); o.z = LEAKY(v2); o.w = LEAKY(v3);
            } else if (EPI == 3) {
                o.x = tanhf(ap[0] + bias[c]);     o.y = tanhf(ap[1] + bias[c + 1]);
                o.z = tanhf(ap[2] + bias[c + 2]); o.w = tanhf(ap[3] + bias[c + 3]);
            } else { // EPI == 4
                float4 old = *(float4*)(crow + c);
                o.x = old.x / (1.f + expf(-(ap[0] + bias[c])));
                o.y = old.y / (1.f + expf(-(ap[1] + bias[c + 1])));
                o.z = old.z / (1.f + expf(-(ap[2] + bias[c + 2])));
                o.w = old.w / (1.f + expf(-(ap[3] + bias[c + 3])));
            }
            *(float4*)(crow + c) = o;
        }
    }
}

// ---------------------------------------------------------------------------
// Segment-sum scatter: agg[dst[e]-rm] += x[src[e]-rm], 512 f32 per edge.
// One wave per edge (64 lanes x 2 float4).
// ---------------------------------------------------------------------------
__global__ void scatter_kernel(const float* __restrict__ x, float* __restrict__ agg,
                               const int* __restrict__ src, const int* __restrict__ dst,
                               int nE, int rm)
{
    int e = (blockIdx.x << 2) + (threadIdx.x >> 6);
    if (e >= nE) return;
    int lane = threadIdx.x & 63;
    int s = src[e] - rm;
    int d = dst[e] - rm;
    const float4* xr = (const float4*)(x + (size_t)s * 512);
    float* ar = agg + (size_t)d * 512;
#pragma unroll
    for (int h = 0; h < 2; ++h) {
        float4 v = xr[lane + (h << 6)];
        int c = (lane + (h << 6)) << 2;
        unsafeAtomicAdd(ar + c + 0, v.x);
        unsafeAtomicAdd(ar + c + 1, v.y);
        unsafeAtomicAdd(ar + c + 2, v.z);
        unsafeAtomicAdd(ar + c + 3, v.w);
    }
}

// ---------------------------------------------------------------------------
// Row LayerNorm(512) + leaky; writes to x-region (ld 512) and optional cat
// column (ld = ld2). One wave per row.
// ---------------------------------------------------------------------------
__global__ void ln_leaky_kernel(const float* __restrict__ h, const float* __restrict__ g,
                                const float* __restrict__ b, float* __restrict__ out1,
                                float* __restrict__ out2, int ld2, int rows)
{
    int r = (blockIdx.x << 2) + (threadIdx.x >> 6);
    if (r >= rows) return;
    int lane = threadIdx.x & 63;
    const float4* hr = (const float4*)(h + (size_t)r * 512);
    float4 v0 = hr[lane];
    float4 v1 = hr[lane + 64];
    float s = v0.x + v0.y + v0.z + v0.w + v1.x + v1.y + v1.z + v1.w;
#pragma unroll
    for (int o = 32; o; o >>= 1) s += __shfl_xor(s, o);
    float mu = s * (1.f / 512.f);
    float dx0 = v0.x - mu, dx1 = v0.y - mu, dx2 = v0.z - mu, dx3 = v0.w - mu;
    float dy0 = v1.x - mu, dy1 = v1.y - mu, dy2 = v1.z - mu, dy3 = v1.w - mu;
    float vs = dx0*dx0 + dx1*dx1 + dx2*dx2 + dx3*dx3
             + dy0*dy0 + dy1*dy1 + dy2*dy2 + dy3*dy3;
#pragma unroll
    for (int o = 32; o; o >>= 1) vs += __shfl_xor(vs, o);
    float inv = rsqrtf(vs * (1.f / 512.f) + 1e-5f);
    int c0 = lane << 2, c1 = (lane + 64) << 2;
    float4 g0 = *(const float4*)(g + c0);
    float4 g1 = *(const float4*)(g + c1);
    float4 b0 = *(const float4*)(b + c0);
    float4 b1 = *(const float4*)(b + c1);
    float4 r0, r1;
    float t;
    t = dx0 * inv * g0.x + b0.x; r0.x = LEAKY(t);
    t = dx1 * inv * g0.y + b0.y; r0.y = LEAKY(t);
    t = dx2 * inv * g0.z + b0.z; r0.z = LEAKY(t);
    t = dx3 * inv * g0.w + b0.w; r0.w = LEAKY(t);
    t = dy0 * inv * g1.x + b1.x; r1.x = LEAKY(t);
    t = dy1 * inv * g1.y + b1.y; r1.y = LEAKY(t);
    t = dy2 * inv * g1.z + b1.z; r1.z = LEAKY(t);
    t = dy3 * inv * g1.w + b1.w; r1.w = LEAKY(t);
    float4* p1 = (float4*)(out1 + (size_t)r * 512);
    p1[lane] = r0; p1[lane + 64] = r1;
    if (out2 != nullptr) {
        float4* p2 = (float4*)(out2 + (size_t)r * ld2);
        p2[lane] = r0; p2[lane + 64] = r1;
    }
}

// cat[:,0:512] column copy
__global__ void cat_copy_kernel(const float* __restrict__ x, float* __restrict__ cat, int rows)
{
    int idx = blockIdx.x * 256 + threadIdx.x;   // float4 index
    int r = idx >> 7;
    int c = idx & 127;
    if (r < rows)
        *((float4*)(cat + (size_t)r * 1536) + c) =
            *((const float4*)(x + (size_t)r * 512) + c);
}

// score[r] = dot(t[r,:1536], w) + b3  (one wave per row)
__global__ void score_kernel(const float* __restrict__ t, const float* __restrict__ w,
                             const float* __restrict__ b3, float* __restrict__ sc, int rows)
{
    int r = (blockIdx.x << 2) + (threadIdx.x >> 6);
    if (r >= rows) return;
    int lane = threadIdx.x & 63;
    const float4* tr = (const float4*)(t + (size_t)r * 1536);
    const float4* wr = (const float4*)w;
    float acc = 0.f;
#pragma unroll
    for (int i = 0; i < 6; ++i) {
        float4 x4 = tr[lane + (i << 6)];
        float4 w4 = wr[lane + (i << 6)];
        acc += x4.x * w4.x + x4.y * w4.y + x4.z * w4.z + x4.w * w4.w;
    }
#pragma unroll
    for (int o = 32; o; o >>= 1) acc += __shfl_xor(acc, o);
    if (lane == 0) sc[r] = acc + b3[0];
}

// single-block softmax stats (max, sumexp)
__global__ void softmax_stats_kernel(const float* __restrict__ a, int n, float* __restrict__ stats)
{
    __shared__ float red[16];
    int tid = threadIdx.x;
    float mx = -3.4e38f;
    for (int i = tid; i < n; i += 1024) mx = fmaxf(mx, a[i]);
#pragma unroll
    for (int o = 32; o; o >>= 1) mx = fmaxf(mx, __shfl_xor(mx, o));
    if ((tid & 63) == 0) red[tid >> 6] = mx;
    __syncthreads();
    float m2 = red[tid & 15];
#pragma unroll
    for (int o = 8; o; o >>= 1) m2 = fmaxf(m2, __shfl_xor(m2, o));
    mx = m2;   // every thread has global max now
    float s = 0.f;
    for (int i = tid; i < n; i += 1024) s += expf(a[i] - mx);
#pragma unroll
    for (int o = 32; o; o >>= 1) s += __shfl_xor(s, o);
    __syncthreads();   // all reads of red done before reuse
    if ((tid & 63) == 0) red[tid >> 6] = s;
    __syncthreads();
    if (tid == 0) {
        float t = 0.f;
        for (int w = 0; w < 16; ++w) t += red[w];
        stats[0] = mx; stats[1] = t;
    }
}

__global__ void att_write_kernel(const float* __restrict__ a, const float* __restrict__ stats,
                                 float* __restrict__ o, int n)
{
    int i = blockIdx.x * 256 + threadIdx.x;
    if (i < n) o[i] = expf(a[i] - stats[0]) / stats[1];
}

// xv[c] += sum_r att[r] * xs[r, c]   (grid (6, 64))
__global__ void colsum_kernel(const float* __restrict__ xs, const float* __restrict__ att,
                              float* __restrict__ xv, int rows)
{
    int c = blockIdx.x * 256 + threadIdx.x;   // 0..1535
    float acc = 0.f;
    for (int r = blockIdx.y; r < rows; r += 64)
        acc += att[r] * xs[(size_t)r * 1536 + c];
    unsafeAtomicAdd(&xv[c], acc);
}

// xv2raw[n] += sum_{k in chunk} xv[k]*W[k,n]   (grid (18,16))
__global__ void lastmm_kernel(const float* __restrict__ xv, const float* __restrict__ W,
                              float* __restrict__ outraw)
{
    int n = blockIdx.x * 256 + threadIdx.x;   // 0..4607
    int k0 = blockIdx.y * 288;
    float acc = 0.f;
    for (int k = k0; k < k0 + 288; ++k)
        acc += xv[k] * W[(size_t)k * 4608 + n];
    unsafeAtomicAdd(&outraw[n], acc);
}

// final: xv2 = leaky(raw + last_b); pred = sigmoid(xv2 @ cla_w + cla_b)
__global__ void pred_kernel(const float* __restrict__ raw, const float* __restrict__ lb,
                            const float* __restrict__ cw, const float* __restrict__ cb,
                            float* __restrict__ out)
{
    __shared__ float xs_[4608];
    __shared__ float red0[8], red1[8];
    int tid = threadIdx.x;   // 512 threads
    for (int k = tid; k < 4608; k += 512) {
        float v = raw[k] + lb[k];
        xs_[k] = LEAKY(v);
    }
    __syncthreads();
    float s0 = 0.f, s1 = 0.f;
    for (int k = tid; k < 4608; k += 512) {
        float v = xs_[k];
        s0 += v * cw[k * 2];
        s1 += v * cw[k * 2 + 1];
    }
#pragma unroll
    for (int o = 32; o; o >>= 1) { s0 += __shfl_xor(s0, o); s1 += __shfl_xor(s1, o); }
    if ((tid & 63) == 0) { red0[tid >> 6] = s0; red1[tid >> 6] = s1; }
    __syncthreads();
    if (tid == 0) {
        float a = 0.f, b = 0.f;
        for (int w = 0; w < 8; ++w) { a += red0[w]; b += red1[w]; }
        out[0] = 1.f / (1.f + expf(-(a + cb[0])));
        out[1] = 1.f / (1.f + expf(-(b + cb[1])));
    }
}

// ---------------------------------------------------------------------------
extern "C" void kernel_launch(void* const* d_in, const int* in_sizes, int n_in,
                              void* d_out, int out_size, void* d_ws, size_t ws_size,
                              hipStream_t stream)
{
    (void)in_sizes; (void)n_in; (void)out_size;

    const float* X          = (const float*)d_in[0];
    const int*   e0         = (const int*)d_in[1];
    const int*   e1         = (const int*)d_in[2];
    const int*   e2         = (const int*)d_in[3];
    const int*   ed0        = (const int*)d_in[4];
    const int*   ed1        = (const int*)d_in[5];
    const float* w0         = (const float*)d_in[6];
    const float* b0         = (const float*)d_in[7];
    const float* conv_wrel  = (const float*)d_in[8];
    const float* conv_brel  = (const float*)d_in[9];
    const float* conv_wroot = (const float*)d_in[10];
    const float* conv_lng   = (const float*)d_in[11];
    const float* conv_lnb   = (const float*)d_in[12];
    const float* diff_wrel  = (const float*)d_in[13];
    const float* diff_brel  = (const float*)d_in[14];
    const float* diff_wroot = (const float*)d_in[15];
    const float* diff_lng   = (const float*)d_in[16];
    const float* diff_lnb   = (const float*)d_in[17];
    const float* attl1_w    = (const float*)d_in[18];
    const float* attl1_b    = (const float*)d_in[19];
    const float* att1_w     = (const float*)d_in[20];
    const float* att1_b     = (const float*)d_in[21];
    const float* att2_w     = (const float*)d_in[22];
    const float* att2_b     = (const float*)d_in[23];
    const float* att3_w     = (const float*)d_in[24];
    const float* att3_b     = (const float*)d_in[25];
    const float* last_w     = (const float*)d_in[26];
    const float* last_b     = (const float*)d_in[27];
    const float* cla_w      = (const float*)d_in[28];
    const float* cla_b      = (const float*)d_in[29];
    float* out = (float*)d_out;

    // workspace layout (floats)
    float* ws   = (float*)d_ws;
    float* Bx   = ws;                        // 112000*512        = 57,344,000
    float* Agg  = Bx  + 57344000;            // 96000*512         = 49,152,000
    float* U    = Agg + 49152000;            // max(h_tmp, xs)    = 98,304,000
    float* Cat  = U   + 98304000;            // 64000*1536        = 98,304,000
    float* Sc   = Cat + 98304000;            // 64,000
    float* Stats= Sc  + 64000;               // 16
    float* Xv   = Stats + 16;                // 4608
    float* Xv2  = Xv  + 4608;                // 4608
    const size_t needed = (size_t)(57344000ULL + 49152000ULL + 98304000ULL +
                                   98304000ULL + 64000ULL + 16ULL + 4608ULL + 4608ULL) * 4ULL;
    if (ws_size < needed) return;   // ws too small: bail (diagnosable as ~zero outputs)

    auto gemm = [&](const float* A, const float* Wm, const float* bias, float* C,
                    int M, int N, int K, int ldc, int epi) {
        dim3 grid(M / 128, N / 128);
        switch (epi) {
        case 0: gemm_f32<0><<<grid, 256, 0, stream>>>(A, Wm, bias, C, N, K, ldc); break;
        case 1: gemm_f32<1><<<grid, 256, 0, stream>>>(A, Wm, bias, C, N, K, ldc); break;
        case 2: gemm_f32<2><<<grid, 256, 0, stream>>>(A, Wm, bias, C, N, K, ldc); break;
        case 3: gemm_f32<3><<<grid, 256, 0, stream>>>(A, Wm, bias, C, N, K, ldc); break;
        case 4: gemm_f32<4><<<grid, 256, 0, stream>>>(A, Wm, bias, C, N, K, ldc); break;
        }
    };

    auto gcn = [&](int rmLoc, int nrows, const int* eptr, int nE,
                   const float* wrel, const float* brel, const float* wroot,
                   const float* lng, const float* lnb, float* cat_col) {
        hipMemsetAsync(Agg, 0, (size_t)nrows * 512 * sizeof(float), stream);
        scatter_kernel<<<nE / 4, 256, 0, stream>>>(
            Bx + (size_t)rmLoc * 512, Agg, eptr, eptr + nE, nE, rmLoc);
        gemm(Agg, wrel, brel, U, nrows, 512, 512, 512, 0);
        gemm(Bx + (size_t)rmLoc * 512, wroot, nullptr, U, nrows, 512, 512, 512, 2);
        ln_leaky_kernel<<<nrows / 4, 256, 0, stream>>>(
            U, lng, lnb, Bx + (size_t)rmLoc * 512, cat_col, 1536, nrows);
    };

    // 1) initial: Bx = leaky(X @ w0 + b0)
    gemm(X, w0, b0, Bx, 112000, 512, 1024, 512, 1);
    hipMemsetAsync(Xv, 0, 4608 * sizeof(float), stream);

    const int PS[3]     = {16000, 32000, 64000};
    const int* convE[3] = {e0, e1, e2};
    const int* diffE[2] = {ed0, ed1};
    const int attoff[3] = {0, 16000, 48000};

    int rm = 0;
    for (int i = 0; i < 3; ++i) {
        const int sz = PS[i];
        // cat col 0 = current x region
        cat_copy_kernel<<<sz / 2, 256, 0, stream>>>(Bx + (size_t)rm * 512, Cat, sz);
        // two conv GCN layers
        for (int j = 0; j < 2; ++j) {
            const int wofs = (i * 2 + j) * 512 * 512;
            const int bofs = (i * 2 + j) * 512;
            gcn(rm, sz, convE[i], sz * 8,
                conv_wrel + wofs, conv_brel + bofs, conv_wroot + wofs,
                conv_lng + bofs, conv_lnb + bofs, Cat + (size_t)(j + 1) * 512);
        }
        // attention for partition i
        const size_t w2 = (size_t)i * 1536 * 1536;
        const size_t bo = (size_t)i * 1536;
        gemm(Cat, attl1_w + w2, attl1_b + bo, U,   sz, 1536, 1536, 1536, 1); // xs
        gemm(U,   att1_w  + w2, att1_b  + bo, Cat, sz, 1536, 1536, 1536, 3); // t = tanh
        gemm(U,   att2_w  + w2, att2_b  + bo, Cat, sz, 1536, 1536, 1536, 4); // t *= sigmoid
        score_kernel<<<sz / 4, 256, 0, stream>>>(Cat, att3_w + bo, att3_b + i, Sc, sz);
        softmax_stats_kernel<<<1, 1024, 0, stream>>>(Sc, sz, Stats);
        att_write_kernel<<<(sz + 255) / 256, 256, 0, stream>>>(
            Sc, Stats, out + 2 + attoff[i], sz);
        colsum_kernel<<<dim3(6, 64), 256, 0, stream>>>(
            U, out + 2 + attoff[i], Xv + (size_t)i * 1536, sz);
        // diff GCN
        if (i < 2) {
            gcn(rm, sz + PS[i + 1], diffE[i], (sz + PS[i + 1]) * 8,
                diff_wrel + (size_t)i * 512 * 512, diff_brel + (size_t)i * 512,
                diff_wroot + (size_t)i * 512 * 512,
                diff_lng + (size_t)i * 512, diff_lnb + (size_t)i * 512, nullptr);
            rm += sz;
        }
    }

    // final MLP head
    hipMemsetAsync(Xv2, 0, 4608 * sizeof(float), stream);
    lastmm_kernel<<<dim3(18, 16), 256, 0, stream>>>(Xv, last_w, Xv2);
    pred_kernel<<<1, 512, 0, stream>>>(Xv2, last_b, cla_w, cla_b, out);
}